// Round 3
// baseline (331.043 us; speedup 1.0000x reference)
//
#include <hip/hip_runtime.h>
#include <math.h>

#define BS 2
#define NQ 21760
#define V_LEN 21760
#define EMBED 256
#define NH 8
#define NL 4
#define NP 4
#define HD 32

typedef _Float16 f16;
typedef _Float16 half8 __attribute__((ext_vector_type(8)));
typedef _Float16 half4v __attribute__((ext_vector_type(4)));
typedef float f32x4 __attribute__((ext_vector_type(4)));

__device__ __forceinline__ void load_lds16(const void* g, void* l) {
    __builtin_amdgcn_global_load_lds(
        (const __attribute__((address_space(1))) void*)g,
        (__attribute__((address_space(3))) void*)l, 16, 0, 0);
}

// ---------------- prep: transpose+cast all weights to f16 WT[n][k], concat bias.
// Row map: [0,256) WTv | [256,640) WToa (W_off 256 cols then W_attn 128) | [640,896) WTu
__global__ __launch_bounds__(256) void prep(
    const float* __restrict__ W_v, const float* __restrict__ W_off,
    const float* __restrict__ W_attn, const float* __restrict__ W_out,
    const float* __restrict__ b_off, const float* __restrict__ b_attn,
    f16* __restrict__ WTv, f16* __restrict__ WToa, f16* __restrict__ WTu,
    float* __restrict__ bcat)
{
    const int nb = blockIdx.x;
    const int k = threadIdx.x;
    if (nb < 256) {
        WTv[nb * 256 + k] = (f16)W_v[k * 256 + nb];
    } else if (nb < 640) {
        int j = nb - 256;
        float w = (j < 256) ? W_off[k * 256 + j] : W_attn[k * 128 + (j - 256)];
        WToa[j * 256 + k] = (f16)w;
    } else if (nb < 896) {
        int j = nb - 640;
        WTu[j * 256 + k] = (f16)W_out[k * 256 + j];
    } else if (nb == 896) {
        bcat[k] = b_off[k];
        if (k < 128) bcat[256 + k] = b_attn[k];
    }
}

// ---------------- GEMM: C[M,N] = A[M,256] @ WT^T + bias. Tile BM=64 x BN=128, BK=32.
// WT: [N][256] f16. A fp32 (cast in staging) or f16 (DMA). 256 threads = 4 waves;
// each wave computes 64x32 strip (4x2 frags of 16x16x32_f16).
// LDS slot layout (unpadded, DMA-compatible): slot S = kcg*ROWS + row, 16B per slot.
template<bool AF16, bool OUTF16>
__global__ __launch_bounds__(256) void gemm_mfma(
    const void* __restrict__ Av, const f16* __restrict__ WT,
    const float* __restrict__ bias, void* __restrict__ Cv,
    int N, int ntn)
{
    const int bnt = blockIdx.x % ntn;
    const int bmt = blockIdx.x / ntn;
    const int bm = bmt * 64, bn = bnt * 128;
    const int K = 256;

    __shared__ __align__(16) f16 As[4 * 64 * 8];    // 4 KB
    __shared__ __align__(16) f16 Bs[4 * 128 * 8];   // 8 KB

    const int tid = threadIdx.x;
    const int lane = tid & 63, wv = tid >> 6;
    const int quad = lane >> 4, l16 = lane & 15;

    f32x4 acc[4][2];
    #pragma unroll
    for (int i = 0; i < 4; i++)
        #pragma unroll
        for (int j = 0; j < 2; j++)
            acc[i][j] = (f32x4){0.f, 0.f, 0.f, 0.f};

    for (int k0 = 0; k0 < K; k0 += 32) {
        // ---- stage B via DMA: 512 slots, 2 issues/thread
        #pragma unroll
        for (int i = 0; i < 2; i++) {
            int S0 = (i * 4 + wv) * 64;
            int S = S0 + lane;
            int col = S & 127, kcg = S >> 7;
            load_lds16(&WT[(size_t)(bn + col) * K + k0 + kcg * 8], &Bs[S0 * 8]);
        }
        // ---- stage A
        if constexpr (AF16) {
            const f16* A = (const f16*)Av;
            int S0 = wv * 64;
            int S = S0 + lane;
            int row = S & 63, kcg = S >> 6;
            load_lds16(&A[(size_t)(bm + row) * K + k0 + kcg * 8], &As[S0 * 8]);
        } else {
            const float* A = (const float*)Av;
            #pragma unroll
            for (int i = 0; i < 2; i++) {
                int F = i * 256 + tid;          // 512 float4 chunks
                int row = F >> 3, kq = F & 7;
                float4 f = *(const float4*)&A[(size_t)(bm + row) * K + k0 + kq * 4];
                half4v h;
                h[0] = (f16)f.x; h[1] = (f16)f.y; h[2] = (f16)f.z; h[3] = (f16)f.w;
                *(half4v*)&As[((kq >> 1) * 64 + row) * 8 + (kq & 1) * 4] = h;
            }
        }
        __syncthreads();

        half8 af[4], bf[2];
        #pragma unroll
        for (int mi = 0; mi < 4; mi++)
            af[mi] = *(const half8*)&As[(quad * 64 + mi * 16 + l16) * 8];
        #pragma unroll
        for (int ni = 0; ni < 2; ni++)
            bf[ni] = *(const half8*)&Bs[(quad * 128 + wv * 32 + ni * 16 + l16) * 8];
        #pragma unroll
        for (int mi = 0; mi < 4; mi++)
            #pragma unroll
            for (int ni = 0; ni < 2; ni++)
                acc[mi][ni] = __builtin_amdgcn_mfma_f32_16x16x32_f16(
                    af[mi], bf[ni], acc[mi][ni], 0, 0, 0);
        __syncthreads();
    }

    #pragma unroll
    for (int mi = 0; mi < 4; mi++) {
        #pragma unroll
        for (int ni = 0; ni < 2; ni++) {
            const int col = bn + wv * 32 + ni * 16 + l16;
            const int row0 = bm + mi * 16 + quad * 4;
            const float bc = bias[col];
            #pragma unroll
            for (int r = 0; r < 4; r++) {
                float v = acc[mi][ni][r] + bc;
                if constexpr (OUTF16)
                    ((f16*)Cv)[(size_t)(row0 + r) * N + col] = (f16)v;
                else
                    ((float*)Cv)[(size_t)(row0 + r) * N + col] = v;
            }
        }
    }
}

// ---------------- Deformable sampling: 256 threads = 4 waves, one query per wave.
// vproj/sampled f16; offaw fp32 [BS*NQ,384] (off 0..255, logits 256..383).
__global__ __launch_bounds__(256) void deform_sample(
    const f16* __restrict__ vproj, const float* __restrict__ offaw,
    const float* __restrict__ refp, f16* __restrict__ sampled)
{
    const int wv = threadIdx.x >> 6;
    const int lane = threadIdx.x & 63;
    const int q = blockIdx.x * 4 + wv;
    const int b = blockIdx.y;
    const int bq = b * NQ + q;

    __shared__ float s_off[4][256];
    __shared__ float s_aw[4][128];
    __shared__ __align__(16) float s_w[4][128][4];
    __shared__ __align__(16) int   s_idx[4][128][4];

    const float* row = offaw + (size_t)bq * 384;
    #pragma unroll
    for (int i = 0; i < 4; i++) s_off[wv][lane + i * 64] = row[lane + i * 64];
    #pragma unroll
    for (int i = 0; i < 2; i++) s_aw[wv][lane + i * 64] = row[256 + lane + i * 64];
    __syncthreads();

    // softmax per head (8 groups of 16)
    if (lane < 8) {
        float m = -1e30f;
        #pragma unroll
        for (int i = 0; i < 16; i++) m = fmaxf(m, s_aw[wv][lane * 16 + i]);
        float ssum = 0.f;
        #pragma unroll
        for (int i = 0; i < 16; i++) {
            float e = __expf(s_aw[wv][lane * 16 + i] - m);
            s_aw[wv][lane * 16 + i] = e;
            ssum += e;
        }
        float r = 1.0f / ssum;
        #pragma unroll
        for (int i = 0; i < 16; i++) s_aw[wv][lane * 16 + i] *= r;
    }
    __syncthreads();

    // precompute 128 samples. Storage index d = lp*8 + h; lane computes d = lane+64*sI
    // (contiguous writes -> no bank conflicts; reads by head -> spread ✓)
    #pragma unroll
    for (int sI = 0; sI < 2; sI++) {
        int d = lane + sI * 64;
        int h = d & 7, lp = d >> 3, l = lp >> 2, p = lp & 3;
        int Wl = 128 >> l;
        int st = (l == 0) ? 0 : (l == 1) ? 16384 : (l == 2) ? 20480 : 21504;
        float rx = refp[(size_t)bq * 8 + l * 2 + 0];
        float ry = refp[(size_t)bq * 8 + l * 2 + 1];
        float ox = s_off[wv][((h * NL + l) * NP + p) * 2 + 0];
        float oy = s_off[wv][((h * NL + l) * NP + p) * 2 + 1];
        float fW = (float)Wl;
        float x = (rx + ox / fW) * fW - 0.5f;
        float y = (ry + oy / fW) * fW - 0.5f;
        float xf = floorf(x), yf = floorf(y);
        int x0 = (int)xf, y0 = (int)yf;
        float wx1 = x - xf, wx0 = 1.f - wx1;
        float wy1 = y - yf, wy0 = 1.f - wy1;
        float aw = s_aw[wv][h * 16 + lp];
        bool vx0 = (x0 >= 0) && (x0 < Wl);
        bool vx1 = (x0 + 1 >= 0) && (x0 + 1 < Wl);
        bool vy0 = (y0 >= 0) && (y0 < Wl);
        bool vy1 = (y0 + 1 >= 0) && (y0 + 1 < Wl);
        int cx0 = min(max(x0, 0), Wl - 1), cx1 = min(max(x0 + 1, 0), Wl - 1);
        int cy0 = min(max(y0, 0), Wl - 1), cy1 = min(max(y0 + 1, 0), Wl - 1);
        // pre-scaled byte offsets (row * 256ch * 2B = <<9)
        s_idx[wv][d][0] = (st + cy0 * Wl + cx0) << 9;  s_w[wv][d][0] = (vy0 && vx0) ? wy0 * wx0 * aw : 0.f;
        s_idx[wv][d][1] = (st + cy0 * Wl + cx1) << 9;  s_w[wv][d][1] = (vy0 && vx1) ? wy0 * wx1 * aw : 0.f;
        s_idx[wv][d][2] = (st + cy1 * Wl + cx0) << 9;  s_w[wv][d][2] = (vy1 && vx0) ? wy1 * wx0 * aw : 0.f;
        s_idx[wv][d][3] = (st + cy1 * Wl + cx1) << 9;  s_w[wv][d][3] = (vy1 && vx1) ? wy1 * wx1 * aw : 0.f;
    }
    __syncthreads();

    // gather: lane owns head h = lane>>3, 4 channels at byte offset lane*8
    const int h = lane >> 3;
    const unsigned int cb = (unsigned int)lane * 8u;
    const char* vb = (const char*)(vproj + (size_t)b * V_LEN * EMBED);
    float a0 = 0.f, a1 = 0.f, a2 = 0.f, a3 = 0.f;
    #pragma unroll 4
    for (int lp = 0; lp < 16; lp++) {
        const int d = lp * 8 + h;
        const float4 w4 = *(const float4*)&s_w[wv][d][0];
        const int4  i4 = *(const int4*)&s_idx[wv][d][0];
        half4v v0 = *(const half4v*)(vb + ((unsigned int)i4.x + cb));
        half4v v1 = *(const half4v*)(vb + ((unsigned int)i4.y + cb));
        half4v v2 = *(const half4v*)(vb + ((unsigned int)i4.z + cb));
        half4v v3 = *(const half4v*)(vb + ((unsigned int)i4.w + cb));
        a0 += w4.x * (float)v0[0] + w4.y * (float)v1[0] + w4.z * (float)v2[0] + w4.w * (float)v3[0];
        a1 += w4.x * (float)v0[1] + w4.y * (float)v1[1] + w4.z * (float)v2[1] + w4.w * (float)v3[1];
        a2 += w4.x * (float)v0[2] + w4.y * (float)v1[2] + w4.z * (float)v2[2] + w4.w * (float)v3[2];
        a3 += w4.x * (float)v0[3] + w4.y * (float)v1[3] + w4.z * (float)v2[3] + w4.w * (float)v3[3];
    }

    half4v o;
    o[0] = (f16)a0; o[1] = (f16)a1; o[2] = (f16)a2; o[3] = (f16)a3;
    *(half4v*)&sampled[(size_t)bq * 256 + lane * 4] = o;
}

extern "C" void kernel_launch(void* const* d_in, const int* in_sizes, int n_in,
                              void* d_out, int out_size, void* d_ws, size_t ws_size,
                              hipStream_t stream)
{
    const float* query  = (const float*)d_in[0];
    const float* refp   = (const float*)d_in[1];
    const float* value  = (const float*)d_in[2];
    const float* W_off  = (const float*)d_in[3];
    const float* b_off  = (const float*)d_in[4];
    const float* W_attn = (const float*)d_in[5];
    const float* b_attn = (const float*)d_in[6];
    const float* W_v    = (const float*)d_in[7];
    const float* b_v    = (const float*)d_in[8];
    const float* W_out  = (const float*)d_in[9];
    const float* b_out  = (const float*)d_in[10];
    float* out = (float*)d_out;

    const int M = BS * NQ;  // 43520

    char* ws = (char*)d_ws;
    f16*   WTv   = (f16*)ws;    ws += 256 * 256 * 2;
    f16*   WToa  = (f16*)ws;    ws += 384 * 256 * 2;
    f16*   WTu   = (f16*)ws;    ws += 256 * 256 * 2;
    float* bcat  = (float*)ws;  ws += 384 * 4 + 128;  // keep 128B alignment
    f16*   vproj = (f16*)ws;    ws += (size_t)M * 256 * 2;
    float* offaw = (float*)ws;  ws += (size_t)M * 384 * 4;
    f16*   samp  = (f16*)ws;    ws += (size_t)M * 256 * 2;

    prep<<<897, 256, 0, stream>>>(W_v, W_off, W_attn, W_out, b_off, b_attn,
                                  WTv, WToa, WTu, bcat);
    // vproj = f16(value @ W_v + b_v)
    gemm_mfma<false, true><<<(M / 64) * 2, 256, 0, stream>>>(value, WTv, b_v, vproj, 256, 2);
    // offaw = query @ [W_off | W_attn] + bias  (fp32)
    gemm_mfma<false, false><<<(M / 64) * 3, 256, 0, stream>>>(query, WToa, bcat, offaw, 384, 3);
    // softmax + deformable sampling -> f16
    deform_sample<<<dim3(NQ / 4, BS), 256, 0, stream>>>(vproj, offaw, refp, samp);
    // out = samp @ W_out + b_out  (fp32)
    gemm_mfma<true, false><<<(M / 64) * 2, 256, 0, stream>>>(samp, WTu, b_out, out, 256, 2);
}

// Round 4
// 311.560 us; speedup vs baseline: 1.0625x; 1.0625x over previous
//
#include <hip/hip_runtime.h>
#include <math.h>

#define BS 2
#define NQ 21760
#define V_LEN 21760
#define EMBED 256
#define NH 8
#define NL 4
#define NP 4
#define HD 32

typedef _Float16 f16;
typedef _Float16 half8 __attribute__((ext_vector_type(8)));
typedef _Float16 half4v __attribute__((ext_vector_type(4)));
typedef float f32x4 __attribute__((ext_vector_type(4)));

__device__ __forceinline__ void load_lds16(const void* g, void* l) {
    __builtin_amdgcn_global_load_lds(
        (const __attribute__((address_space(1))) void*)g,
        (__attribute__((address_space(3))) void*)l, 16, 0, 0);
}

// ---------------- prep: transpose+cast all weights to f16 WT[n][k], concat bias.
__global__ __launch_bounds__(256) void prep(
    const float* __restrict__ W_v, const float* __restrict__ W_off,
    const float* __restrict__ W_attn, const float* __restrict__ W_out,
    const float* __restrict__ b_off, const float* __restrict__ b_attn,
    f16* __restrict__ WTv, f16* __restrict__ WToa, f16* __restrict__ WTu,
    float* __restrict__ bcat)
{
    const int nb = blockIdx.x;
    const int k = threadIdx.x;
    if (nb < 256) {
        WTv[nb * 256 + k] = (f16)W_v[k * 256 + nb];
    } else if (nb < 640) {
        int j = nb - 256;
        float w = (j < 256) ? W_off[k * 256 + j] : W_attn[k * 128 + (j - 256)];
        WToa[j * 256 + k] = (f16)w;
    } else if (nb < 896) {
        int j = nb - 640;
        WTu[j * 256 + k] = (f16)W_out[k * 256 + j];
    } else if (nb == 896) {
        bcat[k] = b_off[k];
        if (k < 128) bcat[256 + k] = b_attn[k];
    }
}

// ---------------- 128x128 MFMA GEMM core. K=256, BK=32 (8 k-steps).
// LDS slot layout (16B slots, DMA-compatible): A slot = kcg*128+row, B slot = kcg*128+col.
// 4 waves in 2x2 grid; each wave 64x64 = 4x4 frags of 16x16x32_f16.
template<bool AF16>
__device__ __forceinline__ void gemm128_core(
    const void* __restrict__ Av, const f16* __restrict__ WT,
    const float* __restrict__ bias, void* __restrict__ Cv,
    int N, int bm, int bn, bool outF16)
{
    const int K = 256;
    __shared__ __align__(16) f16 As[4 * 128 * 8];   // 8 KB
    __shared__ __align__(16) f16 Bs[4 * 128 * 8];   // 8 KB

    const int tid = threadIdx.x;
    const int lane = tid & 63, wv = tid >> 6;
    const int wr = wv >> 1, wc = wv & 1;
    const int quad = lane >> 4, l16 = lane & 15;

    f32x4 acc[4][4];
    #pragma unroll
    for (int i = 0; i < 4; i++)
        #pragma unroll
        for (int j = 0; j < 4; j++)
            acc[i][j] = (f32x4){0.f, 0.f, 0.f, 0.f};

    for (int k0 = 0; k0 < K; k0 += 32) {
        // ---- stage B via DMA: 512 slots, 2 issues/thread
        #pragma unroll
        for (int i = 0; i < 2; i++) {
            int S0 = (i * 4 + wv) * 64;
            int S = S0 + lane;
            int col = S & 127, kcg = S >> 7;
            load_lds16(&WT[(size_t)(bn + col) * K + k0 + kcg * 8], &Bs[S0 * 8]);
        }
        // ---- stage A
        if constexpr (AF16) {
            const f16* A = (const f16*)Av;
            #pragma unroll
            for (int i = 0; i < 2; i++) {
                int S0 = (i * 4 + wv) * 64;
                int S = S0 + lane;
                int row = S & 127, kcg = S >> 7;
                load_lds16(&A[(size_t)(bm + row) * K + k0 + kcg * 8], &As[S0 * 8]);
            }
        } else {
            const float* A = (const float*)Av;
            #pragma unroll
            for (int i = 0; i < 4; i++) {
                int F = i * 256 + tid;          // 1024 float4 chunks
                int row = F >> 3, kq = F & 7;   // 8 float4 per row
                float4 f = *(const float4*)&A[(size_t)(bm + row) * K + k0 + kq * 4];
                half4v h;
                h[0] = (f16)f.x; h[1] = (f16)f.y; h[2] = (f16)f.z; h[3] = (f16)f.w;
                *(half4v*)&As[((kq >> 1) * 128 + row) * 8 + (kq & 1) * 4] = h;
            }
        }
        __syncthreads();

        half8 af[4], bf[4];
        #pragma unroll
        for (int mi = 0; mi < 4; mi++)
            af[mi] = *(const half8*)&As[(quad * 128 + wr * 64 + mi * 16 + l16) * 8];
        #pragma unroll
        for (int ni = 0; ni < 4; ni++)
            bf[ni] = *(const half8*)&Bs[(quad * 128 + wc * 64 + ni * 16 + l16) * 8];
        #pragma unroll
        for (int mi = 0; mi < 4; mi++)
            #pragma unroll
            for (int ni = 0; ni < 4; ni++)
                acc[mi][ni] = __builtin_amdgcn_mfma_f32_16x16x32_f16(
                    af[mi], bf[ni], acc[mi][ni], 0, 0, 0);
        __syncthreads();
    }

    #pragma unroll
    for (int mi = 0; mi < 4; mi++) {
        #pragma unroll
        for (int ni = 0; ni < 4; ni++) {
            const int col = bn + wc * 64 + ni * 16 + l16;
            const int row0 = bm + wr * 64 + mi * 16 + quad * 4;
            const float bc = bias[col];
            if (outF16) {
                #pragma unroll
                for (int r = 0; r < 4; r++)
                    ((f16*)Cv)[(size_t)(row0 + r) * N + col] = (f16)(acc[mi][ni][r] + bc);
            } else {
                #pragma unroll
                for (int r = 0; r < 4; r++)
                    ((float*)Cv)[(size_t)(row0 + r) * N + col] = acc[mi][ni][r] + bc;
            }
        }
    }
}

// Fused front GEMMs: blocks [0,680) -> vproj = f16(value@W_v+b_v), N=256
//                    blocks [680,1700) -> offaw = query@[W_off|W_attn]+bcat (fp32), N=384
__global__ __launch_bounds__(256) void front_gemm(
    const float* __restrict__ value, const float* __restrict__ query,
    const f16* __restrict__ WTv, const f16* __restrict__ WToa,
    const float* __restrict__ b_v, const float* __restrict__ bcat,
    f16* __restrict__ vproj, float* __restrict__ offaw)
{
    int bid = blockIdx.x;
    if (bid < 680) {
        int bnt = bid & 1, bmt = bid >> 1;
        gemm128_core<false>(value, WTv, b_v, vproj, 256, bmt * 128, bnt * 128, true);
    } else {
        int b2 = bid - 680;
        int bnt = b2 % 3, bmt = b2 / 3;
        gemm128_core<false>(query, WToa, bcat, offaw, 384, bmt * 128, bnt * 128, false);
    }
}

__global__ __launch_bounds__(256) void out_gemm(
    const f16* __restrict__ samp, const f16* __restrict__ WTu,
    const float* __restrict__ b_out, float* __restrict__ out)
{
    int bnt = blockIdx.x & 1, bmt = blockIdx.x >> 1;
    gemm128_core<true>(samp, WTu, b_out, out, 256, bmt * 128, bnt * 128, false);
}

// ---------------- Deformable sampling: 256 threads = 4 waves, one query per wave.
__global__ __launch_bounds__(256) void deform_sample(
    const f16* __restrict__ vproj, const float* __restrict__ offaw,
    const float* __restrict__ refp, f16* __restrict__ sampled)
{
    const int wv = threadIdx.x >> 6;
    const int lane = threadIdx.x & 63;
    const int q = blockIdx.x * 4 + wv;
    const int b = blockIdx.y;
    const int bq = b * NQ + q;

    __shared__ float s_off[4][256];
    __shared__ float s_aw[4][128];
    __shared__ __align__(16) f16  s_w[4][128][4];   // f16 weights: 4 KB
    __shared__ __align__(16) int  s_idx[4][128][4]; // 8 KB

    const float* row = offaw + (size_t)bq * 384;
    #pragma unroll
    for (int i = 0; i < 4; i++) s_off[wv][lane + i * 64] = row[lane + i * 64];
    #pragma unroll
    for (int i = 0; i < 2; i++) s_aw[wv][lane + i * 64] = row[256 + lane + i * 64];
    __syncthreads();

    if (lane < 8) {
        float m = -1e30f;
        #pragma unroll
        for (int i = 0; i < 16; i++) m = fmaxf(m, s_aw[wv][lane * 16 + i]);
        float ssum = 0.f;
        #pragma unroll
        for (int i = 0; i < 16; i++) {
            float e = __expf(s_aw[wv][lane * 16 + i] - m);
            s_aw[wv][lane * 16 + i] = e;
            ssum += e;
        }
        float r = 1.0f / ssum;
        #pragma unroll
        for (int i = 0; i < 16; i++) s_aw[wv][lane * 16 + i] *= r;
    }
    __syncthreads();

    // precompute 128 samples; storage d = lp*8 + h, lane computes d = lane+64*sI
    #pragma unroll
    for (int sI = 0; sI < 2; sI++) {
        int d = lane + sI * 64;
        int h = d & 7, lp = d >> 3, l = lp >> 2, p = lp & 3;
        int Wl = 128 >> l;
        int st = (l == 0) ? 0 : (l == 1) ? 16384 : (l == 2) ? 20480 : 21504;
        float rx = refp[(size_t)bq * 8 + l * 2 + 0];
        float ry = refp[(size_t)bq * 8 + l * 2 + 1];
        float ox = s_off[wv][((h * NL + l) * NP + p) * 2 + 0];
        float oy = s_off[wv][((h * NL + l) * NP + p) * 2 + 1];
        float fW = (float)Wl;
        float x = (rx + ox / fW) * fW - 0.5f;
        float y = (ry + oy / fW) * fW - 0.5f;
        float xf = floorf(x), yf = floorf(y);
        int x0 = (int)xf, y0 = (int)yf;
        float wx1 = x - xf, wx0 = 1.f - wx1;
        float wy1 = y - yf, wy0 = 1.f - wy1;
        float aw = s_aw[wv][h * 16 + lp];
        bool vx0 = (x0 >= 0) && (x0 < Wl);
        bool vx1 = (x0 + 1 >= 0) && (x0 + 1 < Wl);
        bool vy0 = (y0 >= 0) && (y0 < Wl);
        bool vy1 = (y0 + 1 >= 0) && (y0 + 1 < Wl);
        int cx0 = min(max(x0, 0), Wl - 1), cx1 = min(max(x0 + 1, 0), Wl - 1);
        int cy0 = min(max(y0, 0), Wl - 1), cy1 = min(max(y0 + 1, 0), Wl - 1);
        half4v w4;
        w4[0] = (f16)((vy0 && vx0) ? wy0 * wx0 * aw : 0.f);
        w4[1] = (f16)((vy0 && vx1) ? wy0 * wx1 * aw : 0.f);
        w4[2] = (f16)((vy1 && vx0) ? wy1 * wx0 * aw : 0.f);
        w4[3] = (f16)((vy1 && vx1) ? wy1 * wx1 * aw : 0.f);
        *(half4v*)&s_w[wv][d][0] = w4;
        int4 i4;
        i4.x = (st + cy0 * Wl + cx0) << 9;  // byte offsets (row * 512B)
        i4.y = (st + cy0 * Wl + cx1) << 9;
        i4.z = (st + cy1 * Wl + cx0) << 9;
        i4.w = (st + cy1 * Wl + cx1) << 9;
        *(int4*)&s_idx[wv][d][0] = i4;
    }
    __syncthreads();

    // gather: lane owns head h = lane>>3, 4 channels at byte offset lane*8
    const int h = lane >> 3;
    const unsigned int cb = (unsigned int)lane * 8u;
    const char* vb = (const char*)(vproj + (size_t)b * V_LEN * EMBED);
    float a0 = 0.f, a1 = 0.f, a2 = 0.f, a3 = 0.f;
    #pragma unroll 8
    for (int lp = 0; lp < 16; lp++) {
        const int d = lp * 8 + h;
        const half4v w4 = *(const half4v*)&s_w[wv][d][0];
        const int4  i4 = *(const int4*)&s_idx[wv][d][0];
        half4v v0 = *(const half4v*)(vb + ((unsigned int)i4.x + cb));
        half4v v1 = *(const half4v*)(vb + ((unsigned int)i4.y + cb));
        half4v v2 = *(const half4v*)(vb + ((unsigned int)i4.z + cb));
        half4v v3 = *(const half4v*)(vb + ((unsigned int)i4.w + cb));
        a0 += (float)w4[0] * (float)v0[0] + (float)w4[1] * (float)v1[0] + (float)w4[2] * (float)v2[0] + (float)w4[3] * (float)v3[0];
        a1 += (float)w4[0] * (float)v0[1] + (float)w4[1] * (float)v1[1] + (float)w4[2] * (float)v2[1] + (float)w4[3] * (float)v3[1];
        a2 += (float)w4[0] * (float)v0[2] + (float)w4[1] * (float)v1[2] + (float)w4[2] * (float)v2[2] + (float)w4[3] * (float)v3[2];
        a3 += (float)w4[0] * (float)v0[3] + (float)w4[1] * (float)v1[3] + (float)w4[2] * (float)v2[3] + (float)w4[3] * (float)v3[3];
    }

    half4v o;
    o[0] = (f16)a0; o[1] = (f16)a1; o[2] = (f16)a2; o[3] = (f16)a3;
    *(half4v*)&sampled[(size_t)bq * 256 + lane * 4] = o;
}

extern "C" void kernel_launch(void* const* d_in, const int* in_sizes, int n_in,
                              void* d_out, int out_size, void* d_ws, size_t ws_size,
                              hipStream_t stream)
{
    const float* query  = (const float*)d_in[0];
    const float* refp   = (const float*)d_in[1];
    const float* value  = (const float*)d_in[2];
    const float* W_off  = (const float*)d_in[3];
    const float* b_off  = (const float*)d_in[4];
    const float* W_attn = (const float*)d_in[5];
    const float* b_attn = (const float*)d_in[6];
    const float* W_v    = (const float*)d_in[7];
    const float* b_v    = (const float*)d_in[8];
    const float* W_out  = (const float*)d_in[9];
    const float* b_out  = (const float*)d_in[10];
    float* out = (float*)d_out;

    const int M = BS * NQ;  // 43520

    char* ws = (char*)d_ws;
    f16*   WTv   = (f16*)ws;    ws += 256 * 256 * 2;
    f16*   WToa  = (f16*)ws;    ws += 384 * 256 * 2;
    f16*   WTu   = (f16*)ws;    ws += 256 * 256 * 2;
    float* bcat  = (float*)ws;  ws += 384 * 4 + 128;
    f16*   vproj = (f16*)ws;    ws += (size_t)M * 256 * 2;
    float* offaw = (float*)ws;  ws += (size_t)M * 384 * 4;
    f16*   samp  = (f16*)ws;    ws += (size_t)M * 256 * 2;

    prep<<<897, 256, 0, stream>>>(W_v, W_off, W_attn, W_out, b_off, b_attn,
                                  WTv, WToa, WTu, bcat);
    front_gemm<<<1700, 256, 0, stream>>>(value, query, WTv, WToa, b_v, bcat,
                                         vproj, offaw);
    deform_sample<<<dim3(NQ / 4, BS), 256, 0, stream>>>(vproj, offaw, refp, samp);
    out_gemm<<<680, 256, 0, stream>>>(samp, WTu, b_out, out);
}